// Round 9
// baseline (165.199 us; speedup 1.0000x reference)
//
#include <hip/hip_runtime.h>
#include <hip/hip_bf16.h>
#include <math.h>

#define TAU_INV_LOG2E 14.4269504088896340736f  // (1/0.1) * log2(e)
#define EPS 1e-8f

typedef __attribute__((ext_vector_type(8))) short bf16x8;
typedef __attribute__((ext_vector_type(8))) unsigned short u16x8;
typedef __attribute__((ext_vector_type(4))) float f32x4;

static __device__ __forceinline__ unsigned short f2bf(float f) {
    unsigned int u = __float_as_uint(f);
    unsigned int r = (u + 0x7fffu + ((u >> 16) & 1u)) >> 16;
    return (unsigned short)r;
}

// Kernel 1: L2-normalize rows AND repack into fragment-native layout xf.
// xf unit (rt, kc, lane): 16B at ((rt*8+kc)*64 + lane)*8 shorts holding
//   xn[rt*16 + (lane&15)][kc*32 + (lane>>4)*8 .. +7]
// so a gemm wave loads an entire MFMA fragment with ONE coalesced
// global_load_dwordx4 (64 lanes x 16B contiguous = 1KB).
__global__ __launch_bounds__(256) void normalize_repack_kernel(
    const float* __restrict__ x, unsigned short* __restrict__ xf,
    float* __restrict__ out, int N) {
    __shared__ unsigned short xs[16 * 264];  // stride 264 shorts (2-way banks)
    const int t   = threadIdx.x;
    const int rt  = blockIdx.x;
    const int r   = t >> 4;
    const int c16 = t & 15;
    if (rt == 0 && t == 0) out[0] = 0.0f;

    const float* xr = x + ((size_t)rt * 16 + r) * 256 + c16 * 16;
    const float4 v0 = ((const float4*)xr)[0];
    const float4 v1 = ((const float4*)xr)[1];
    const float4 v2 = ((const float4*)xr)[2];
    const float4 v3 = ((const float4*)xr)[3];
    float s = v0.x*v0.x + v0.y*v0.y + v0.z*v0.z + v0.w*v0.w
            + v1.x*v1.x + v1.y*v1.y + v1.z*v1.z + v1.w*v1.w
            + v2.x*v2.x + v2.y*v2.y + v2.z*v2.z + v2.w*v2.w
            + v3.x*v3.x + v3.y*v3.y + v3.z*v3.z + v3.w*v3.w;
    s += __shfl_xor(s, 1);
    s += __shfl_xor(s, 2);
    s += __shfl_xor(s, 4);
    s += __shfl_xor(s, 8);
    const float rinv = 1.0f / fmaxf(sqrtf(s), 1e-12f);

    u16x8 w0, w1;
    w0[0] = f2bf(v0.x * rinv); w0[1] = f2bf(v0.y * rinv);
    w0[2] = f2bf(v0.z * rinv); w0[3] = f2bf(v0.w * rinv);
    w0[4] = f2bf(v1.x * rinv); w0[5] = f2bf(v1.y * rinv);
    w0[6] = f2bf(v1.z * rinv); w0[7] = f2bf(v1.w * rinv);
    w1[0] = f2bf(v2.x * rinv); w1[1] = f2bf(v2.y * rinv);
    w1[2] = f2bf(v2.z * rinv); w1[3] = f2bf(v2.w * rinv);
    w1[4] = f2bf(v3.x * rinv); w1[5] = f2bf(v3.y * rinv);
    w1[6] = f2bf(v3.z * rinv); w1[7] = f2bf(v3.w * rinv);
    *(u16x8*)(&xs[r * 264 + c16 * 16 + 0]) = w0;
    *(u16x8*)(&xs[r * 264 + c16 * 16 + 8]) = w1;
    __syncthreads();

    #pragma unroll
    for (int uu = 0; uu < 2; ++uu) {
        const int u   = t + uu * 256;         // 0..511
        const int kc  = u >> 6;
        const int ln  = u & 63;
        const int q   = ln >> 4;
        const int l16 = ln & 15;
        const u16x8 d = *(const u16x8*)(&xs[l16 * 264 + kc * 32 + q * 8]);
        *(u16x8*)(xf + (size_t)rt * 4096 + (size_t)u * 8) = d;
    }
}

// Kernel 2: symmetric fused S = Xn*Xn^T on upper-triangle 128x128 tiles.
// Compute identical to round 8 (no LDS, no barriers, fragment-native loads).
// NEW: (1) bijective XCD-chunked SUPERTILE-major tile order -- the 64x64 tile
// triangle is split into 8x8 supertiles (36 supertiles; diag=36 tiles,
// off-diag=64; total 2080 = 8*260). Each XCD gets a contiguous 260-tile chunk
// of the supertile-major linearization, so its instantaneous working set is
// ~16 panels = 1 MB << 4 MB L2 (vs sweeping the full 4 MB with LRU wraparound
// under the old round-robin order). (2) nontemporal prow stores so the write
// streams don't evict the resident panels from L2.
// Atomic-free epilogue slots (unique writer per cell, order-independent):
//   row-partials (64 cols of wave w)  -> prowR[2*bj+w],  rows of bi
//   col-partials (full 128-row sums)  -> prowC[bi],      rows of bj (!diag)
__global__ __launch_bounds__(128, 2) void gemm_frag_kernel(
    const unsigned short* __restrict__ xf, float* __restrict__ prowR,
    float* __restrict__ prowC, int N) {
    const int tid  = threadIdx.x;
    const int w    = tid >> 6;
    const int lane = tid & 63;
    const int quad = lane >> 4;
    const int l16  = lane & 15;

    // ---- tile decode: XCD-chunked supertile-major (bijective) ----
    const int B   = N >> 7;               // 64 tiles/dim
    const int B8  = B >> 3;               // 8 supertile rows
    const int T   = (B * (B + 1)) >> 1;   // 2080
    const int chk = T >> 3;               // 260 tiles per XCD chunk
    const int bid = blockIdx.x;
    int tp = (bid & 7) * chk + (bid >> 3);  // supertile-major linear index

    int si = 0, sj = 0, base = 0;
    for (si = 0; si < B8; ++si) {
        bool done = false;
        for (sj = si; sj < B8; ++sj) {
            const int sz = (si == sj) ? 36 : 64;
            if (tp < base + sz) { done = true; break; }
            base += sz;
        }
        if (done) break;
    }
    int u = tp - base;
    int di, dj;
    if (si == sj) {                        // triangle decode inside 8x8 diag
        di = 0; int a2 = 0;
        while (u >= a2 + (8 - di)) { a2 += 8 - di; ++di; }
        dj = di + (u - a2);
    } else { di = u >> 3; dj = u & 7; }
    const int bi = si * 8 + di;
    const int bj = sj * 8 + dj;
    const bool diag = (bi == bj);

    const size_t lane8 = (size_t)lane * 8;
    const unsigned short* Ab = xf + (size_t)(bi * 8) * 4096;          // rt = bi*8+mt
    const unsigned short* Bb = xf + (size_t)(bj * 8 + w * 4) * 4096;  // rt = .. + nt

    f32x4 acc[8][4];
    #pragma unroll
    for (int mt = 0; mt < 8; ++mt)
        #pragma unroll
        for (int nt = 0; nt < 4; ++nt)
            acc[mt][nt] = (f32x4){0.f, 0.f, 0.f, 0.f};

    #pragma unroll
    for (int kc = 0; kc < 8; ++kc) {
        bf16x8 a[8], b[4];
        #pragma unroll
        for (int mt = 0; mt < 8; ++mt)
            a[mt] = *(const bf16x8*)(Ab + ((size_t)mt * 8 + kc) * 512 + lane8);
        #pragma unroll
        for (int nt = 0; nt < 4; ++nt)
            b[nt] = *(const bf16x8*)(Bb + ((size_t)nt * 8 + kc) * 512 + lane8);
        #pragma unroll
        for (int mt = 0; mt < 8; ++mt)
            #pragma unroll
            for (int nt = 0; nt < 4; ++nt)
                acc[mt][nt] = __builtin_amdgcn_mfma_f32_16x16x32_bf16(
                    a[mt], b[nt], acc[mt][nt], 0, 0, 0);
    }

    // Epilogue. C/D layout: col = l16, row = quad*4 + reg  [m89/m91]
    const int iBase = bi * 128;
    const int jBase = bj * 128;
    float rsum[8][4];
    float csum[4] = {0.f, 0.f, 0.f, 0.f};
    #pragma unroll
    for (int mt = 0; mt < 8; ++mt)
        #pragma unroll
        for (int r = 0; r < 4; ++r) rsum[mt][r] = 0.f;

    #pragma unroll
    for (int mt = 0; mt < 8; ++mt) {
        const int gi0 = iBase + mt * 16 + quad * 4;
        #pragma unroll
        for (int nt = 0; nt < 4; ++nt) {
            const int gj = jBase + w * 64 + nt * 16 + l16;
            #pragma unroll
            for (int r = 0; r < 4; ++r) {
                float e = __builtin_amdgcn_exp2f(acc[mt][nt][r] * TAU_INV_LOG2E);
                if (gi0 + r == gj) e = 0.0f;  // diagonal (diag tiles only)
                rsum[mt][r] += e;
                csum[nt] += e;
            }
        }
    }
    // row partials (this wave's 64 cols) -> prowR slot 2*bj+w, rows of bi
    {
        float* slot = prowR + (size_t)(2 * bj + w) * N;
        #pragma unroll
        for (int mt = 0; mt < 8; ++mt) {
            const int gi0 = iBase + mt * 16 + quad * 4;
            #pragma unroll
            for (int r = 0; r < 4; ++r) {
                float s = rsum[mt][r];
                s += __shfl_xor(s, 1);
                s += __shfl_xor(s, 2);
                s += __shfl_xor(s, 4);
                s += __shfl_xor(s, 8);
                if (l16 == 0)
                    __builtin_nontemporal_store(s, &slot[gi0 + r]);
            }
        }
    }
    // col partials (full 128-row sums; symmetry) -> prowC slot bi, rows of bj
    if (!diag) {
        float* slot = prowC + (size_t)bi * N;
        #pragma unroll
        for (int nt = 0; nt < 4; ++nt) {
            float s = csum[nt];
            s += __shfl_xor(s, 16);
            s += __shfl_xor(s, 32);
            if (quad == 0)
                __builtin_nontemporal_store(
                    s, &slot[jBase + w * 64 + nt * 16 + l16]);
        }
    }
}

// Kernel 3: row i (block a = i>>7): rowsum_i = sum prowR[p>=2a] + prowC[p<a];
// loss += log(rowsum/(N-1)+eps)/N. 32 blocks x 256 threads (a wave-uniform).
__global__ __launch_bounds__(256) void finalize_kernel(
    const float* __restrict__ prowR, const float* __restrict__ prowC,
    float* __restrict__ out, int N) {
    __shared__ float red[4];
    const int i = blockIdx.x * 256 + threadIdx.x;
    const int a = i >> 7;
    float s = 0.f;
    for (int p = 2 * a; p < 128; ++p) s += prowR[(size_t)p * N + i];
    for (int p = 0; p < a; ++p)       s += prowC[(size_t)p * N + i];
    float acc = logf(fmaf(s, 1.0f / (float)(N - 1), EPS));
    acc += __shfl_xor(acc, 1);
    acc += __shfl_xor(acc, 2);
    acc += __shfl_xor(acc, 4);
    acc += __shfl_xor(acc, 8);
    acc += __shfl_xor(acc, 16);
    acc += __shfl_xor(acc, 32);
    const int wave = threadIdx.x >> 6;
    const int lane = threadIdx.x & 63;
    if (lane == 0) red[wave] = acc;
    __syncthreads();
    if (threadIdx.x == 0)
        atomicAdd(out, (red[0] + red[1] + red[2] + red[3]) / (float)N);
}

extern "C" void kernel_launch(void* const* d_in, const int* in_sizes, int n_in,
                              void* d_out, int out_size, void* d_ws, size_t ws_size,
                              hipStream_t stream) {
    const float* x = (const float*)d_in[0];
    const int D = 256;
    const int N = in_sizes[0] / D;  // 8192
    const int B = N / 128;          // 64

    unsigned short* xf = (unsigned short*)d_ws;                 // 4 MB
    float* prowR = (float*)((char*)d_ws + (size_t)N * D * 2);   // 128 x N = 4 MB
    float* prowC = prowR + (size_t)128 * N;                     // 64 x N = 2 MB
    float* out = (float*)d_out;

    normalize_repack_kernel<<<N / 16, 256, 0, stream>>>(x, xf, out, N);

    const int T = B * (B + 1) / 2;  // 2080 upper-triangle tiles
    gemm_frag_kernel<<<T, 128, 0, stream>>>(xf, prowR, prowC, N);

    finalize_kernel<<<N / 256, 256, 0, stream>>>(prowR, prowC, out, N);
}

// Round 10
// 146.586 us; speedup vs baseline: 1.1270x; 1.1270x over previous
//
#include <hip/hip_runtime.h>
#include <hip/hip_bf16.h>
#include <math.h>

#define TAU_INV_LOG2E 14.4269504088896340736f  // (1/0.1) * log2(e)
#define EPS 1e-8f

typedef __attribute__((ext_vector_type(8))) short bf16x8;
typedef __attribute__((ext_vector_type(8))) unsigned short u16x8;
typedef __attribute__((ext_vector_type(4))) float f32x4;

static __device__ __forceinline__ unsigned short f2bf(float f) {
    unsigned int u = __float_as_uint(f);
    unsigned int r = (u + 0x7fffu + ((u >> 16) & 1u)) >> 16;
    return (unsigned short)r;
}

// Kernel 1: L2-normalize rows AND repack into fragment-native layout xf.
// xf unit (rt, kc, lane): 16B at ((rt*8+kc)*64 + lane)*8 shorts holding
//   xn[rt*16 + (lane&15)][kc*32 + (lane>>4)*8 .. +7]
// so one coalesced dwordx4 per wave loads an entire MFMA fragment.
__global__ __launch_bounds__(256) void normalize_repack_kernel(
    const float* __restrict__ x, unsigned short* __restrict__ xf,
    float* __restrict__ out, int N) {
    __shared__ unsigned short xs[16 * 264];  // stride 264 shorts (2-way banks)
    const int t   = threadIdx.x;
    const int rt  = blockIdx.x;
    const int r   = t >> 4;
    const int c16 = t & 15;
    if (rt == 0 && t == 0) out[0] = 0.0f;

    const float* xr = x + ((size_t)rt * 16 + r) * 256 + c16 * 16;
    const float4 v0 = ((const float4*)xr)[0];
    const float4 v1 = ((const float4*)xr)[1];
    const float4 v2 = ((const float4*)xr)[2];
    const float4 v3 = ((const float4*)xr)[3];
    float s = v0.x*v0.x + v0.y*v0.y + v0.z*v0.z + v0.w*v0.w
            + v1.x*v1.x + v1.y*v1.y + v1.z*v1.z + v1.w*v1.w
            + v2.x*v2.x + v2.y*v2.y + v2.z*v2.z + v2.w*v2.w
            + v3.x*v3.x + v3.y*v3.y + v3.z*v3.z + v3.w*v3.w;
    s += __shfl_xor(s, 1);
    s += __shfl_xor(s, 2);
    s += __shfl_xor(s, 4);
    s += __shfl_xor(s, 8);
    const float rinv = 1.0f / fmaxf(sqrtf(s), 1e-12f);

    u16x8 w0, w1;
    w0[0] = f2bf(v0.x * rinv); w0[1] = f2bf(v0.y * rinv);
    w0[2] = f2bf(v0.z * rinv); w0[3] = f2bf(v0.w * rinv);
    w0[4] = f2bf(v1.x * rinv); w0[5] = f2bf(v1.y * rinv);
    w0[6] = f2bf(v1.z * rinv); w0[7] = f2bf(v1.w * rinv);
    w1[0] = f2bf(v2.x * rinv); w1[1] = f2bf(v2.y * rinv);
    w1[2] = f2bf(v2.z * rinv); w1[3] = f2bf(v2.w * rinv);
    w1[4] = f2bf(v3.x * rinv); w1[5] = f2bf(v3.y * rinv);
    w1[6] = f2bf(v3.z * rinv); w1[7] = f2bf(v3.w * rinv);
    *(u16x8*)(&xs[r * 264 + c16 * 16 + 0]) = w0;
    *(u16x8*)(&xs[r * 264 + c16 * 16 + 8]) = w1;
    __syncthreads();

    #pragma unroll
    for (int uu = 0; uu < 2; ++uu) {
        const int u   = t + uu * 256;         // 0..511
        const int kc  = u >> 6;
        const int ln  = u & 63;
        const int q   = ln >> 4;
        const int l16 = ln & 15;
        const u16x8 d = *(const u16x8*)(&xs[l16 * 264 + kc * 32 + q * 8]);
        *(u16x8*)(xf + (size_t)rt * 4096 + (size_t)u * 8) = d;
    }
}

// Kernel 2: symmetric fused S = Xn*Xn^T on upper-triangle 128x128 tiles.
// No LDS, no barriers (fragment-native coalesced loads from L2-resident xf,
// supertile-XCD-chunked tile order). NEW vs r8/r9: 4 waves per block, each
// wave owns a 64x64 quadrant -> acc = 64 regs (not 128), and the kc loop is
// explicitly software-pipelined with TWO named fragment buffers (64 regs,
// statically indexed). __launch_bounds__(256,3) caps regs at 170 -> 3
// waves/SIMD; batched next-kc loads hide L2 latency under current-kc MFMAs
// instead of serializing (the r8/r9 failure mode).
// Atomic-free epilogue slots (unique writer per cell, order-independent):
//   row-partials (wM row-half, wN col-half) -> prowR[2*bj+wN], rows of bi
//   col-partials (wM row-half sums)         -> prowC[2*bi+wM], rows of bj
__global__ __launch_bounds__(256, 3) void gemm_frag_kernel(
    const unsigned short* __restrict__ xf, float* __restrict__ prowR,
    float* __restrict__ prowC, int N) {
    const int tid   = threadIdx.x;
    const int wave  = tid >> 6;
    const int lane  = tid & 63;
    const int waveM = wave >> 1;
    const int waveN = wave & 1;
    const int quad  = lane >> 4;
    const int l16   = lane & 15;

    // ---- tile decode: XCD-chunked supertile-major (bijective, r9-proven) ----
    const int B   = N >> 7;               // 64 tiles/dim
    const int B8  = B >> 3;               // 8 supertile rows
    const int T   = (B * (B + 1)) >> 1;   // 2080
    const int chk = T >> 3;               // 260 tiles per XCD chunk
    const int bid = blockIdx.x;
    int tp = (bid & 7) * chk + (bid >> 3);

    int si = 0, sj = 0, base = 0;
    for (si = 0; si < B8; ++si) {
        bool done = false;
        for (sj = si; sj < B8; ++sj) {
            const int sz = (si == sj) ? 36 : 64;
            if (tp < base + sz) { done = true; break; }
            base += sz;
        }
        if (done) break;
    }
    int u = tp - base;
    int di, dj;
    if (si == sj) {
        di = 0; int a2 = 0;
        while (u >= a2 + (8 - di)) { a2 += 8 - di; ++di; }
        dj = di + (u - a2);
    } else { di = u >> 3; dj = u & 7; }
    const int bi = si * 8 + di;
    const int bj = sj * 8 + dj;
    const bool diag = (bi == bj);

    // fragment base pointers for this wave's quadrant
    const size_t lane8 = (size_t)lane * 8;
    const unsigned short* aP =
        xf + (size_t)(bi * 8 + waveM * 4) * 4096 + lane8;   // + mt*4096 + kc*512
    const unsigned short* bP =
        xf + (size_t)(bj * 8 + waveN * 4) * 4096 + lane8;   // + nt*4096 + kc*512

    f32x4 acc[4][4];
    #pragma unroll
    for (int mt = 0; mt < 4; ++mt)
        #pragma unroll
        for (int nt = 0; nt < 4; ++nt)
            acc[mt][nt] = (f32x4){0.f, 0.f, 0.f, 0.f};

    bf16x8 a0[4], b0[4], a1[4], b1[4];

    auto loadf = [&](bf16x8 (&a)[4], bf16x8 (&b)[4], int kc) {
        #pragma unroll
        for (int mt = 0; mt < 4; ++mt)
            a[mt] = *(const bf16x8*)(aP + (size_t)mt * 4096 + (size_t)kc * 512);
        #pragma unroll
        for (int nt = 0; nt < 4; ++nt)
            b[nt] = *(const bf16x8*)(bP + (size_t)nt * 4096 + (size_t)kc * 512);
    };
    auto mfmas = [&](bf16x8 (&a)[4], bf16x8 (&b)[4]) {
        #pragma unroll
        for (int mt = 0; mt < 4; ++mt)
            #pragma unroll
            for (int nt = 0; nt < 4; ++nt)
                acc[mt][nt] = __builtin_amdgcn_mfma_f32_16x16x32_bf16(
                    a[mt], b[nt], acc[mt][nt], 0, 0, 0);
    };

    // software-pipelined kc loop: loads of kc+1 issue before MFMAs of kc
    loadf(a0, b0, 0);
    #pragma unroll
    for (int kc = 0; kc < 8; kc += 2) {
        if (kc + 1 < 8) loadf(a1, b1, kc + 1);
        mfmas(a0, b0);
        if (kc + 2 < 8) loadf(a0, b0, kc + 2);
        if (kc + 1 < 8) mfmas(a1, b1);
    }

    // Epilogue. C/D layout: col = l16, row = quad*4 + reg  [m89/m91]
    const int iBase = bi * 128;
    const int jBase = bj * 128;
    float rsum[4][4];
    float csum[4] = {0.f, 0.f, 0.f, 0.f};
    #pragma unroll
    for (int mt = 0; mt < 4; ++mt)
        #pragma unroll
        for (int r = 0; r < 4; ++r) rsum[mt][r] = 0.f;

    #pragma unroll
    for (int mt = 0; mt < 4; ++mt) {
        const int gi0 = iBase + waveM * 64 + mt * 16 + quad * 4;
        #pragma unroll
        for (int nt = 0; nt < 4; ++nt) {
            const int gj = jBase + waveN * 64 + nt * 16 + l16;
            #pragma unroll
            for (int r = 0; r < 4; ++r) {
                float e = __builtin_amdgcn_exp2f(acc[mt][nt][r] * TAU_INV_LOG2E);
                if (gi0 + r == gj) e = 0.0f;  // diagonal (diag tiles only)
                rsum[mt][r] += e;
                csum[nt] += e;
            }
        }
    }
    // row partials -> prowR slot 2*bj+waveN, rows of bi (waveM half)
    {
        float* slot = prowR + (size_t)(2 * bj + waveN) * N;
        #pragma unroll
        for (int mt = 0; mt < 4; ++mt) {
            const int gi0 = iBase + waveM * 64 + mt * 16 + quad * 4;
            #pragma unroll
            for (int r = 0; r < 4; ++r) {
                float s = rsum[mt][r];
                s += __shfl_xor(s, 1);
                s += __shfl_xor(s, 2);
                s += __shfl_xor(s, 4);
                s += __shfl_xor(s, 8);
                if (l16 == 0)
                    __builtin_nontemporal_store(s, &slot[gi0 + r]);
            }
        }
    }
    // col partials (symmetry) -> prowC slot 2*bi+waveM, rows of bj (waveN half)
    if (!diag) {
        float* slot = prowC + (size_t)(2 * bi + waveM) * N;
        #pragma unroll
        for (int nt = 0; nt < 4; ++nt) {
            float s = csum[nt];
            s += __shfl_xor(s, 16);
            s += __shfl_xor(s, 32);
            if (quad == 0)
                __builtin_nontemporal_store(
                    s, &slot[jBase + waveN * 64 + nt * 16 + l16]);
        }
    }
}

// Kernel 3: row i (block a = i>>7): rowsum_i = prowR slots [2a,128) +
// prowC slots [0,2a); loss += log(rowsum/(N-1)+eps)/N.
__global__ __launch_bounds__(256) void finalize_kernel(
    const float* __restrict__ prowR, const float* __restrict__ prowC,
    float* __restrict__ out, int N) {
    __shared__ float red[4];
    const int i = blockIdx.x * 256 + threadIdx.x;
    const int a = i >> 7;
    float s = 0.f;
    for (int p = 2 * a; p < 128; ++p) s += prowR[(size_t)p * N + i];
    for (int p = 0; p < 2 * a; ++p)  s += prowC[(size_t)p * N + i];
    float acc = logf(fmaf(s, 1.0f / (float)(N - 1), EPS));
    acc += __shfl_xor(acc, 1);
    acc += __shfl_xor(acc, 2);
    acc += __shfl_xor(acc, 4);
    acc += __shfl_xor(acc, 8);
    acc += __shfl_xor(acc, 16);
    acc += __shfl_xor(acc, 32);
    const int wave = threadIdx.x >> 6;
    const int lane = threadIdx.x & 63;
    if (lane == 0) red[wave] = acc;
    __syncthreads();
    if (threadIdx.x == 0)
        atomicAdd(out, (red[0] + red[1] + red[2] + red[3]) / (float)N);
}

extern "C" void kernel_launch(void* const* d_in, const int* in_sizes, int n_in,
                              void* d_out, int out_size, void* d_ws, size_t ws_size,
                              hipStream_t stream) {
    const float* x = (const float*)d_in[0];
    const int D = 256;
    const int N = in_sizes[0] / D;  // 8192
    const int B = N / 128;          // 64

    unsigned short* xf = (unsigned short*)d_ws;                 // 4 MB
    float* prowR = (float*)((char*)d_ws + (size_t)N * D * 2);   // 128 x N = 4 MB
    float* prowC = prowR + (size_t)128 * N;                     // 128 x N = 4 MB
    float* out = (float*)d_out;

    normalize_repack_kernel<<<N / 16, 256, 0, stream>>>(x, xf, out, N);

    const int T = B * (B + 1) / 2;  // 2080 upper-triangle tiles
    gemm_frag_kernel<<<T, 256, 0, stream>>>(xf, prowR, prowC, N);

    finalize_kernel<<<N / 256, 256, 0, stream>>>(prowR, prowC, out, N);
}

// Round 11
// 142.611 us; speedup vs baseline: 1.1584x; 1.0279x over previous
//
#include <hip/hip_runtime.h>
#include <hip/hip_bf16.h>
#include <math.h>

#define TAU_INV_LOG2E 14.4269504088896340736f  // (1/0.1) * log2(e)
#define EPS 1e-8f

typedef __attribute__((ext_vector_type(8))) short bf16x8;
typedef __attribute__((ext_vector_type(8))) unsigned short u16x8;
typedef __attribute__((ext_vector_type(4))) float f32x4;

static __device__ __forceinline__ unsigned short f2bf(float f) {
    unsigned int u = __float_as_uint(f);
    unsigned int r = (u + 0x7fffu + ((u >> 16) & 1u)) >> 16;
    return (unsigned short)r;
}

// Kernel 1: L2-normalize rows AND repack into fragment-native layout xf.
// xf unit (rt, kc, lane): 16B at ((rt*8+kc)*64 + lane)*8 shorts holding
//   xn[rt*16 + (lane&15)][kc*32 + (lane>>4)*8 .. +7]
// so one coalesced dwordx4 per wave loads an entire MFMA fragment.
__global__ __launch_bounds__(256) void normalize_repack_kernel(
    const float* __restrict__ x, unsigned short* __restrict__ xf,
    float* __restrict__ out, int N) {
    __shared__ unsigned short xs[16 * 264];  // stride 264 shorts (2-way banks)
    const int t   = threadIdx.x;
    const int rt  = blockIdx.x;
    const int r   = t >> 4;
    const int c16 = t & 15;
    if (rt == 0 && t == 0) out[0] = 0.0f;

    const float* xr = x + ((size_t)rt * 16 + r) * 256 + c16 * 16;
    const float4 v0 = ((const float4*)xr)[0];
    const float4 v1 = ((const float4*)xr)[1];
    const float4 v2 = ((const float4*)xr)[2];
    const float4 v3 = ((const float4*)xr)[3];
    float s = v0.x*v0.x + v0.y*v0.y + v0.z*v0.z + v0.w*v0.w
            + v1.x*v1.x + v1.y*v1.y + v1.z*v1.z + v1.w*v1.w
            + v2.x*v2.x + v2.y*v2.y + v2.z*v2.z + v2.w*v2.w
            + v3.x*v3.x + v3.y*v3.y + v3.z*v3.z + v3.w*v3.w;
    s += __shfl_xor(s, 1);
    s += __shfl_xor(s, 2);
    s += __shfl_xor(s, 4);
    s += __shfl_xor(s, 8);
    const float rinv = 1.0f / fmaxf(sqrtf(s), 1e-12f);

    u16x8 w0, w1;
    w0[0] = f2bf(v0.x * rinv); w0[1] = f2bf(v0.y * rinv);
    w0[2] = f2bf(v0.z * rinv); w0[3] = f2bf(v0.w * rinv);
    w0[4] = f2bf(v1.x * rinv); w0[5] = f2bf(v1.y * rinv);
    w0[6] = f2bf(v1.z * rinv); w0[7] = f2bf(v1.w * rinv);
    w1[0] = f2bf(v2.x * rinv); w1[1] = f2bf(v2.y * rinv);
    w1[2] = f2bf(v2.z * rinv); w1[3] = f2bf(v2.w * rinv);
    w1[4] = f2bf(v3.x * rinv); w1[5] = f2bf(v3.y * rinv);
    w1[6] = f2bf(v3.z * rinv); w1[7] = f2bf(v3.w * rinv);
    *(u16x8*)(&xs[r * 264 + c16 * 16 + 0]) = w0;
    *(u16x8*)(&xs[r * 264 + c16 * 16 + 8]) = w1;
    __syncthreads();

    #pragma unroll
    for (int uu = 0; uu < 2; ++uu) {
        const int u   = t + uu * 256;         // 0..511
        const int kc  = u >> 6;
        const int ln  = u & 63;
        const int q   = ln >> 4;
        const int l16 = ln & 15;
        const u16x8 d = *(const u16x8*)(&xs[l16 * 264 + kc * 32 + q * 8]);
        *(u16x8*)(xf + (size_t)rt * 4096 + (size_t)u * 8) = d;
    }
}

// Kernel 2: symmetric fused S = Xn*Xn^T on upper-triangle 128x128 tiles.
// Identical to round 10 (no LDS, no barriers, fragment-native coalesced
// loads, supertile-XCD order, 4 waves x 64x64 quadrants, 2-deep named
// fragment pipeline, 3 waves/SIMD) EXCEPT: col partials now write into the
// COMPLEMENTARY slots of the SAME prow array (merged layout):
//   row-partials of tile (bi,bj), wave (wM,wN) -> prow[2*bj+wN], rows of bi
//   col-partials of tile (bi,bj), wave (wM,wN) -> prow[2*bi+wM], rows of bj
// For row-block a: row-partials fill slots [2a,128) (bj>=a, both parities),
// col-partials fill slots [0,2a) (bi<a). Every (row, slot) cell in [0,128)
// is written exactly once -> finalize sums a FIXED 128 slots, no bounds.
__global__ __launch_bounds__(256, 3) void gemm_frag_kernel(
    const unsigned short* __restrict__ xf, float* __restrict__ prow, int N) {
    const int tid   = threadIdx.x;
    const int wave  = tid >> 6;
    const int lane  = tid & 63;
    const int waveM = wave >> 1;
    const int waveN = wave & 1;
    const int quad  = lane >> 4;
    const int l16   = lane & 15;

    // ---- tile decode: XCD-chunked supertile-major (bijective, r9-proven) ----
    const int B   = N >> 7;               // 64 tiles/dim
    const int B8  = B >> 3;               // 8 supertile rows
    const int T   = (B * (B + 1)) >> 1;   // 2080
    const int chk = T >> 3;               // 260 tiles per XCD chunk
    const int bid = blockIdx.x;
    int tp = (bid & 7) * chk + (bid >> 3);

    int si = 0, sj = 0, base = 0;
    for (si = 0; si < B8; ++si) {
        bool done = false;
        for (sj = si; sj < B8; ++sj) {
            const int sz = (si == sj) ? 36 : 64;
            if (tp < base + sz) { done = true; break; }
            base += sz;
        }
        if (done) break;
    }
    int u = tp - base;
    int di, dj;
    if (si == sj) {
        di = 0; int a2 = 0;
        while (u >= a2 + (8 - di)) { a2 += 8 - di; ++di; }
        dj = di + (u - a2);
    } else { di = u >> 3; dj = u & 7; }
    const int bi = si * 8 + di;
    const int bj = sj * 8 + dj;
    const bool diag = (bi == bj);

    // fragment base pointers for this wave's quadrant
    const size_t lane8 = (size_t)lane * 8;
    const unsigned short* aP =
        xf + (size_t)(bi * 8 + waveM * 4) * 4096 + lane8;   // + mt*4096 + kc*512
    const unsigned short* bP =
        xf + (size_t)(bj * 8 + waveN * 4) * 4096 + lane8;   // + nt*4096 + kc*512

    f32x4 acc[4][4];
    #pragma unroll
    for (int mt = 0; mt < 4; ++mt)
        #pragma unroll
        for (int nt = 0; nt < 4; ++nt)
            acc[mt][nt] = (f32x4){0.f, 0.f, 0.f, 0.f};

    bf16x8 a0[4], b0[4], a1[4], b1[4];

    auto loadf = [&](bf16x8 (&a)[4], bf16x8 (&b)[4], int kc) {
        #pragma unroll
        for (int mt = 0; mt < 4; ++mt)
            a[mt] = *(const bf16x8*)(aP + (size_t)mt * 4096 + (size_t)kc * 512);
        #pragma unroll
        for (int nt = 0; nt < 4; ++nt)
            b[nt] = *(const bf16x8*)(bP + (size_t)nt * 4096 + (size_t)kc * 512);
    };
    auto mfmas = [&](bf16x8 (&a)[4], bf16x8 (&b)[4]) {
        #pragma unroll
        for (int mt = 0; mt < 4; ++mt)
            #pragma unroll
            for (int nt = 0; nt < 4; ++nt)
                acc[mt][nt] = __builtin_amdgcn_mfma_f32_16x16x32_bf16(
                    a[mt], b[nt], acc[mt][nt], 0, 0, 0);
    };

    // software-pipelined kc loop: loads of kc+1 issue before MFMAs of kc
    loadf(a0, b0, 0);
    #pragma unroll
    for (int kc = 0; kc < 8; kc += 2) {
        if (kc + 1 < 8) loadf(a1, b1, kc + 1);
        mfmas(a0, b0);
        if (kc + 2 < 8) loadf(a0, b0, kc + 2);
        if (kc + 1 < 8) mfmas(a1, b1);
    }

    // Epilogue. C/D layout: col = l16, row = quad*4 + reg  [m89/m91]
    const int iBase = bi * 128;
    const int jBase = bj * 128;
    float rsum[4][4];
    float csum[4] = {0.f, 0.f, 0.f, 0.f};
    #pragma unroll
    for (int mt = 0; mt < 4; ++mt)
        #pragma unroll
        for (int r = 0; r < 4; ++r) rsum[mt][r] = 0.f;

    #pragma unroll
    for (int mt = 0; mt < 4; ++mt) {
        const int gi0 = iBase + waveM * 64 + mt * 16 + quad * 4;
        #pragma unroll
        for (int nt = 0; nt < 4; ++nt) {
            const int gj = jBase + waveN * 64 + nt * 16 + l16;
            #pragma unroll
            for (int r = 0; r < 4; ++r) {
                float e = __builtin_amdgcn_exp2f(acc[mt][nt][r] * TAU_INV_LOG2E);
                if (gi0 + r == gj) e = 0.0f;  // diagonal (diag tiles only)
                rsum[mt][r] += e;
                csum[nt] += e;
            }
        }
    }
    // row partials -> prow slot 2*bj+waveN, rows of bi (waveM half)
    {
        float* slot = prow + (size_t)(2 * bj + waveN) * N;
        #pragma unroll
        for (int mt = 0; mt < 4; ++mt) {
            const int gi0 = iBase + waveM * 64 + mt * 16 + quad * 4;
            #pragma unroll
            for (int r = 0; r < 4; ++r) {
                float s = rsum[mt][r];
                s += __shfl_xor(s, 1);
                s += __shfl_xor(s, 2);
                s += __shfl_xor(s, 4);
                s += __shfl_xor(s, 8);
                if (l16 == 0)
                    __builtin_nontemporal_store(s, &slot[gi0 + r]);
            }
        }
    }
    // col partials (symmetry) -> prow slot 2*bi+waveM, rows of bj (waveN half)
    if (!diag) {
        float* slot = prow + (size_t)(2 * bi + waveM) * N;
        #pragma unroll
        for (int nt = 0; nt < 4; ++nt) {
            float s = csum[nt];
            s += __shfl_xor(s, 16);
            s += __shfl_xor(s, 32);
            if (quad == 0)
                __builtin_nontemporal_store(
                    s, &slot[jBase + waveN * 64 + nt * 16 + l16]);
        }
    }
}

// Kernel 3: rowsum_i = sum over ALL 128 slots of prow (fixed trip count);
// loss += log(rowsum/(N-1)+eps)/N. Fully unrolled with 8 independent
// accumulators so loads pipeline (the r5-r10 runtime-bounds version
// serialized 128 dependent ~600cy loads -> 53 us hidden tax).
__global__ __launch_bounds__(256) void finalize_kernel(
    const float* __restrict__ prow, float* __restrict__ out, int N) {
    __shared__ float red[4];
    const int i = blockIdx.x * 256 + threadIdx.x;
    float ps[8] = {0.f, 0.f, 0.f, 0.f, 0.f, 0.f, 0.f, 0.f};
    #pragma unroll
    for (int p = 0; p < 128; ++p)
        ps[p & 7] += prow[(size_t)p * N + i];
    float s = ((ps[0] + ps[1]) + (ps[2] + ps[3])) +
              ((ps[4] + ps[5]) + (ps[6] + ps[7]));
    float acc = logf(fmaf(s, 1.0f / (float)(N - 1), EPS));
    acc += __shfl_xor(acc, 1);
    acc += __shfl_xor(acc, 2);
    acc += __shfl_xor(acc, 4);
    acc += __shfl_xor(acc, 8);
    acc += __shfl_xor(acc, 16);
    acc += __shfl_xor(acc, 32);
    const int wave = threadIdx.x >> 6;
    const int lane = threadIdx.x & 63;
    if (lane == 0) red[wave] = acc;
    __syncthreads();
    if (threadIdx.x == 0)
        atomicAdd(out, (red[0] + red[1] + red[2] + red[3]) / (float)N);
}

extern "C" void kernel_launch(void* const* d_in, const int* in_sizes, int n_in,
                              void* d_out, int out_size, void* d_ws, size_t ws_size,
                              hipStream_t stream) {
    const float* x = (const float*)d_in[0];
    const int D = 256;
    const int N = in_sizes[0] / D;  // 8192
    const int B = N / 128;          // 64

    unsigned short* xf = (unsigned short*)d_ws;                 // 4 MB
    float* prow = (float*)((char*)d_ws + (size_t)N * D * 2);    // 128 x N = 4 MB
    float* out = (float*)d_out;

    normalize_repack_kernel<<<N / 16, 256, 0, stream>>>(x, xf, out, N);

    const int T = B * (B + 1) / 2;  // 2080 upper-triangle tiles
    gemm_frag_kernel<<<T, 256, 0, stream>>>(xf, prow, N);

    finalize_kernel<<<N / 256, 256, 0, stream>>>(prow, out, N);
}

// Round 12
// 102.081 us; speedup vs baseline: 1.6183x; 1.3970x over previous
//
#include <hip/hip_runtime.h>
#include <hip/hip_bf16.h>
#include <math.h>

#define TAU_INV_LOG2E 14.4269504088896340736f  // (1/0.1) * log2(e)
#define EPS 1e-8f

typedef __attribute__((ext_vector_type(8))) short bf16x8;
typedef __attribute__((ext_vector_type(8))) unsigned short u16x8;
typedef __attribute__((ext_vector_type(4))) float f32x4;

static __device__ __forceinline__ unsigned short f2bf(float f) {
    unsigned int u = __float_as_uint(f);
    unsigned int r = (u + 0x7fffu + ((u >> 16) & 1u)) >> 16;
    return (unsigned short)r;
}

// Kernel 1: L2-normalize rows AND repack into fragment-native layout xf.
// xf unit (rt, kc, lane): 16B at ((rt*8+kc)*64 + lane)*8 shorts holding
//   xn[rt*16 + (lane&15)][kc*32 + (lane>>4)*8 .. +7]
// so one coalesced dwordx4 per wave loads an entire MFMA fragment.
__global__ __launch_bounds__(256) void normalize_repack_kernel(
    const float* __restrict__ x, unsigned short* __restrict__ xf,
    float* __restrict__ out, int N) {
    __shared__ unsigned short xs[16 * 264];  // stride 264 shorts (2-way banks)
    const int t   = threadIdx.x;
    const int rt  = blockIdx.x;
    const int r   = t >> 4;
    const int c16 = t & 15;
    if (rt == 0 && t == 0) out[0] = 0.0f;

    const float* xr = x + ((size_t)rt * 16 + r) * 256 + c16 * 16;
    const float4 v0 = ((const float4*)xr)[0];
    const float4 v1 = ((const float4*)xr)[1];
    const float4 v2 = ((const float4*)xr)[2];
    const float4 v3 = ((const float4*)xr)[3];
    float s = v0.x*v0.x + v0.y*v0.y + v0.z*v0.z + v0.w*v0.w
            + v1.x*v1.x + v1.y*v1.y + v1.z*v1.z + v1.w*v1.w
            + v2.x*v2.x + v2.y*v2.y + v2.z*v2.z + v2.w*v2.w
            + v3.x*v3.x + v3.y*v3.y + v3.z*v3.z + v3.w*v3.w;
    s += __shfl_xor(s, 1);
    s += __shfl_xor(s, 2);
    s += __shfl_xor(s, 4);
    s += __shfl_xor(s, 8);
    const float rinv = 1.0f / fmaxf(sqrtf(s), 1e-12f);

    u16x8 w0, w1;
    w0[0] = f2bf(v0.x * rinv); w0[1] = f2bf(v0.y * rinv);
    w0[2] = f2bf(v0.z * rinv); w0[3] = f2bf(v0.w * rinv);
    w0[4] = f2bf(v1.x * rinv); w0[5] = f2bf(v1.y * rinv);
    w0[6] = f2bf(v1.z * rinv); w0[7] = f2bf(v1.w * rinv);
    w1[0] = f2bf(v2.x * rinv); w1[1] = f2bf(v2.y * rinv);
    w1[2] = f2bf(v2.z * rinv); w1[3] = f2bf(v2.w * rinv);
    w1[4] = f2bf(v3.x * rinv); w1[5] = f2bf(v3.y * rinv);
    w1[6] = f2bf(v3.z * rinv); w1[7] = f2bf(v3.w * rinv);
    *(u16x8*)(&xs[r * 264 + c16 * 16 + 0]) = w0;
    *(u16x8*)(&xs[r * 264 + c16 * 16 + 8]) = w1;
    __syncthreads();

    #pragma unroll
    for (int uu = 0; uu < 2; ++uu) {
        const int u   = t + uu * 256;         // 0..511
        const int kc  = u >> 6;
        const int ln  = u & 63;
        const int q   = ln >> 4;
        const int l16 = ln & 15;
        const u16x8 d = *(const u16x8*)(&xs[l16 * 264 + kc * 32 + q * 8]);
        *(u16x8*)(xf + (size_t)rt * 4096 + (size_t)u * 8) = d;
    }
}

// Kernel 2: symmetric fused S = Xn*Xn^T on upper-triangle 128x128 tiles.
// Identical compute to rounds 10/11 (no LDS, no barriers, fragment-native
// coalesced loads, supertile-XCD order, 4 waves x 64x64 quadrants, 2-deep
// named fragment pipeline). CHANGE vs r11: plain stores for partials
// (nontemporal evicted prow from cache and poisoned the finalize read path
// -- 48 us of serial HBM latency; r11 post-mortem).
// Merged slot layout (unique writer per (row, slot) cell):
//   row-partials of tile (bi,bj), wave (wM,wN) -> prow[2*bj+wN], rows of bi
//   col-partials of tile (bi,bj), wave (wM,wN) -> prow[2*bi+wM], rows of bj
// For row-block a: slots [2a,128) from row-partials, [0,2a) from
// col-partials -> finalize sums a fixed 128 slots.
__global__ __launch_bounds__(256, 3) void gemm_frag_kernel(
    const unsigned short* __restrict__ xf, float* __restrict__ prow, int N) {
    const int tid   = threadIdx.x;
    const int wave  = tid >> 6;
    const int lane  = tid & 63;
    const int waveM = wave >> 1;
    const int waveN = wave & 1;
    const int quad  = lane >> 4;
    const int l16   = lane & 15;

    // ---- tile decode: XCD-chunked supertile-major (bijective, r9-proven) ----
    const int B   = N >> 7;               // 64 tiles/dim
    const int B8  = B >> 3;               // 8 supertile rows
    const int T   = (B * (B + 1)) >> 1;   // 2080
    const int chk = T >> 3;               // 260 tiles per XCD chunk
    const int bid = blockIdx.x;
    int tp = (bid & 7) * chk + (bid >> 3);

    int si = 0, sj = 0, base = 0;
    for (si = 0; si < B8; ++si) {
        bool done = false;
        for (sj = si; sj < B8; ++sj) {
            const int sz = (si == sj) ? 36 : 64;
            if (tp < base + sz) { done = true; break; }
            base += sz;
        }
        if (done) break;
    }
    int u = tp - base;
    int di, dj;
    if (si == sj) {
        di = 0; int a2 = 0;
        while (u >= a2 + (8 - di)) { a2 += 8 - di; ++di; }
        dj = di + (u - a2);
    } else { di = u >> 3; dj = u & 7; }
    const int bi = si * 8 + di;
    const int bj = sj * 8 + dj;
    const bool diag = (bi == bj);

    // fragment base pointers for this wave's quadrant
    const size_t lane8 = (size_t)lane * 8;
    const unsigned short* aP =
        xf + (size_t)(bi * 8 + waveM * 4) * 4096 + lane8;   // + mt*4096 + kc*512
    const unsigned short* bP =
        xf + (size_t)(bj * 8 + waveN * 4) * 4096 + lane8;   // + nt*4096 + kc*512

    f32x4 acc[4][4];
    #pragma unroll
    for (int mt = 0; mt < 4; ++mt)
        #pragma unroll
        for (int nt = 0; nt < 4; ++nt)
            acc[mt][nt] = (f32x4){0.f, 0.f, 0.f, 0.f};

    bf16x8 a0[4], b0[4], a1[4], b1[4];

    auto loadf = [&](bf16x8 (&a)[4], bf16x8 (&b)[4], int kc) {
        #pragma unroll
        for (int mt = 0; mt < 4; ++mt)
            a[mt] = *(const bf16x8*)(aP + (size_t)mt * 4096 + (size_t)kc * 512);
        #pragma unroll
        for (int nt = 0; nt < 4; ++nt)
            b[nt] = *(const bf16x8*)(bP + (size_t)nt * 4096 + (size_t)kc * 512);
    };
    auto mfmas = [&](bf16x8 (&a)[4], bf16x8 (&b)[4]) {
        #pragma unroll
        for (int mt = 0; mt < 4; ++mt)
            #pragma unroll
            for (int nt = 0; nt < 4; ++nt)
                acc[mt][nt] = __builtin_amdgcn_mfma_f32_16x16x32_bf16(
                    a[mt], b[nt], acc[mt][nt], 0, 0, 0);
    };

    // software-pipelined kc loop: loads of kc+1 issue before MFMAs of kc
    loadf(a0, b0, 0);
    #pragma unroll
    for (int kc = 0; kc < 8; kc += 2) {
        if (kc + 1 < 8) loadf(a1, b1, kc + 1);
        mfmas(a0, b0);
        if (kc + 2 < 8) loadf(a0, b0, kc + 2);
        if (kc + 1 < 8) mfmas(a1, b1);
    }

    // Epilogue. C/D layout: col = l16, row = quad*4 + reg  [m89/m91]
    const int iBase = bi * 128;
    const int jBase = bj * 128;
    float rsum[4][4];
    float csum[4] = {0.f, 0.f, 0.f, 0.f};
    #pragma unroll
    for (int mt = 0; mt < 4; ++mt)
        #pragma unroll
        for (int r = 0; r < 4; ++r) rsum[mt][r] = 0.f;

    #pragma unroll
    for (int mt = 0; mt < 4; ++mt) {
        const int gi0 = iBase + waveM * 64 + mt * 16 + quad * 4;
        #pragma unroll
        for (int nt = 0; nt < 4; ++nt) {
            const int gj = jBase + waveN * 64 + nt * 16 + l16;
            #pragma unroll
            for (int r = 0; r < 4; ++r) {
                float e = __builtin_amdgcn_exp2f(acc[mt][nt][r] * TAU_INV_LOG2E);
                if (gi0 + r == gj) e = 0.0f;  // diagonal (diag tiles only)
                rsum[mt][r] += e;
                csum[nt] += e;
            }
        }
    }
    // row partials -> prow slot 2*bj+waveN, rows of bi (waveM half)
    {
        float* slot = prow + (size_t)(2 * bj + waveN) * N;
        #pragma unroll
        for (int mt = 0; mt < 4; ++mt) {
            const int gi0 = iBase + waveM * 64 + mt * 16 + quad * 4;
            #pragma unroll
            for (int r = 0; r < 4; ++r) {
                float s = rsum[mt][r];
                s += __shfl_xor(s, 1);
                s += __shfl_xor(s, 2);
                s += __shfl_xor(s, 4);
                s += __shfl_xor(s, 8);
                if (l16 == 0) slot[gi0 + r] = s;
            }
        }
    }
    // col partials (symmetry) -> prow slot 2*bi+waveM, rows of bj (waveN half)
    if (!diag) {
        float* slot = prow + (size_t)(2 * bi + waveM) * N;
        #pragma unroll
        for (int nt = 0; nt < 4; ++nt) {
            float s = csum[nt];
            s += __shfl_xor(s, 16);
            s += __shfl_xor(s, 32);
            if (quad == 0)
                slot[jBase + waveN * 64 + nt * 16 + l16] = s;
        }
    }
}

// Kernel 3 (v3): parallel over rows AND slots. 256 blocks x 256 threads.
// Block b owns rows [b*32, b*32+32). Thread t: row i = b*32 + (t&31),
// slot-group g = t>>5 (16 slots each). Each 32-lane half-wave issues
// coalesced 128B loads; 16 independent statically-indexed loads per thread
// (latency amortized by 2048 waves of TLP, not register heroics -- the r11
// version's VGPR=8 serial chain was 48 us). Cross-group combine via LDS;
// one log per row; 256 atomics total.
__global__ __launch_bounds__(256) void finalize_kernel(
    const float* __restrict__ prow, float* __restrict__ out, int N) {
    __shared__ float psum[8][33];
    __shared__ float red;
    const int t = threadIdx.x;
    const int r32 = t & 31;
    const int g   = t >> 5;
    const int i   = blockIdx.x * 32 + r32;

    float v[16];
    #pragma unroll
    for (int k = 0; k < 16; ++k)
        v[k] = prow[(size_t)(g * 16 + k) * N + i];
    float s = ((v[0] + v[1]) + (v[2] + v[3])) + ((v[4] + v[5]) + (v[6] + v[7]))
            + ((v[8] + v[9]) + (v[10] + v[11])) + ((v[12] + v[13]) + (v[14] + v[15]));
    psum[g][r32] = s;
    __syncthreads();

    if (t < 32) {
        float rs = ((psum[0][t] + psum[1][t]) + (psum[2][t] + psum[3][t]))
                 + ((psum[4][t] + psum[5][t]) + (psum[6][t] + psum[7][t]));
        float acc = logf(fmaf(rs, 1.0f / (float)(N - 1), EPS));
        acc += __shfl_xor(acc, 1);
        acc += __shfl_xor(acc, 2);
        acc += __shfl_xor(acc, 4);
        acc += __shfl_xor(acc, 8);
        acc += __shfl_xor(acc, 16);
        if (t == 0) red = acc;
    }
    __syncthreads();
    if (t == 0) atomicAdd(out, red / (float)N);
}

extern "C" void kernel_launch(void* const* d_in, const int* in_sizes, int n_in,
                              void* d_out, int out_size, void* d_ws, size_t ws_size,
                              hipStream_t stream) {
    const float* x = (const float*)d_in[0];
    const int D = 256;
    const int N = in_sizes[0] / D;  // 8192
    const int B = N / 128;          // 64

    unsigned short* xf = (unsigned short*)d_ws;                 // 4 MB
    float* prow = (float*)((char*)d_ws + (size_t)N * D * 2);    // 128 x N = 4 MB
    float* out = (float*)d_out;

    normalize_repack_kernel<<<N / 16, 256, 0, stream>>>(x, xf, out, N);

    const int T = B * (B + 1) / 2;  // 2080 upper-triangle tiles
    gemm_frag_kernel<<<T, 256, 0, stream>>>(xf, prow, N);

    finalize_kernel<<<N / 32, 256, 0, stream>>>(prow, out, N);
}